// Round 1
// baseline (616.830 us; speedup 1.0000x reference)
//
#include <hip/hip_runtime.h>
#include <stdint.h>

// Workspace layout: N x u64 keys. key = ((u64)t << 32) | (u32)(pos + 1).
// key==0  <=> node has no events. Monotone atomicMax reproduces
// "max t, ties -> max pos" exactly.

__global__ void init_ws_kernel(unsigned long long* __restrict__ ws, int n) {
    int i = blockIdx.x * blockDim.x + threadIdx.x;
    if (i < n) ws[i] = 0ULL;
}

__global__ void scatter_max_kernel(const int* __restrict__ t,
                                   const int* __restrict__ idx,
                                   unsigned long long* __restrict__ ws,
                                   int E) {
    int i = blockIdx.x * blockDim.x + threadIdx.x;
    if (i >= E) return;
    unsigned long long key =
        ((unsigned long long)(unsigned int)t[i] << 32) | (unsigned int)(i + 1);
    unsigned long long* p = &ws[idx[i]];
    // Monotone filter: ws values only ever increase within this kernel
    // (init=0, atomicMax). A stale/cached read is always <= the true value,
    // so skipping when (stale >= key) is safe; reading low just costs a
    // redundant atomic. Cuts atomic traffic under 10-way avg contention.
    if (*p < key) {
        atomicMax(p, key);
    }
}

// One node per 32 lanes; each lane moves one float4 (D=128 floats = 32 x float4).
__global__ void gather_kernel(const unsigned long long* __restrict__ ws,
                              const float4* __restrict__ msg,
                              float4* __restrict__ out,
                              int N) {
    int gid = blockIdx.x * blockDim.x + threadIdx.x;
    int node = gid >> 5;
    int lane = gid & 31;
    if (node >= N) return;
    unsigned long long key = ws[node];  // broadcast across the 32 lanes via L1/L2
    float4 v = make_float4(0.f, 0.f, 0.f, 0.f);
    if (key != 0ULL) {
        int pos = (int)(unsigned int)(key & 0xFFFFFFFFULL) - 1;
        v = msg[(size_t)pos * 32 + lane];
    }
    out[(size_t)node * 32 + lane] = v;
}

extern "C" void kernel_launch(void* const* d_in, const int* in_sizes, int n_in,
                              void* d_out, int out_size, void* d_ws, size_t ws_size,
                              hipStream_t stream) {
    const float* msg = (const float*)d_in[0];
    const int* index = (const int*)d_in[1];
    const int* t     = (const int*)d_in[2];
    // d_in[3] is dim_size on device; recover N on host from out_size (= N*128).
    const int D = 128;
    const int E = in_sizes[0] / D;
    const int N = out_size / D;

    unsigned long long* ws = (unsigned long long*)d_ws;

    {
        int threads = 256;
        int blocks = (N + threads - 1) / threads;
        init_ws_kernel<<<blocks, threads, 0, stream>>>(ws, N);
    }
    {
        int threads = 256;
        int blocks = (E + threads - 1) / threads;
        scatter_max_kernel<<<blocks, threads, 0, stream>>>(t, index, ws, E);
    }
    {
        int threads = 256;
        long long total = (long long)N * 32;
        int blocks = (int)((total + threads - 1) / threads);
        gather_kernel<<<blocks, threads, 0, stream>>>(
            ws, (const float4*)msg, (float4*)d_out, N);
    }
}

// Round 2
// 602.473 us; speedup vs baseline: 1.0238x; 1.0238x over previous
//
#include <hip/hip_runtime.h>
#include <stdint.h>

// key = (t << 32) | (pos+1); key==0 <=> empty node.
// Lexicographic u64 max == (max t, ties -> max pos).
static __device__ __forceinline__ unsigned long long pack_key(int t, int pos) {
    return ((unsigned long long)(unsigned int)t << 32) | (unsigned int)(pos + 1);
}

#define T_HI 750000

__global__ void init_ws_kernel(unsigned long long* __restrict__ ws, int n) {
    int i = blockIdx.x * blockDim.x + threadIdx.x;
    if (i < n) ws[i] = 0ULL;
}

// K1: high-t events (~25%) do an unconditional u64 atomicMax.
// No pre-load filter: cached reads may never observe memory-side RMW
// results, so a filter is both useless and adds 64B line fetches/event.
__global__ void __launch_bounds__(256)
scatter_hi_kernel(const int* __restrict__ t, const int* __restrict__ idx,
                  unsigned long long* __restrict__ ws, int E) {
    int i0 = (blockIdx.x * blockDim.x + threadIdx.x) * 4;
    if (i0 + 3 < E) {
        int4 tv = *(const int4*)(t + i0);
        int4 iv = *(const int4*)(idx + i0);
        if (tv.x >= T_HI) atomicMax(&ws[iv.x], pack_key(tv.x, i0 + 0));
        if (tv.y >= T_HI) atomicMax(&ws[iv.y], pack_key(tv.y, i0 + 1));
        if (tv.z >= T_HI) atomicMax(&ws[iv.z], pack_key(tv.z, i0 + 2));
        if (tv.w >= T_HI) atomicMax(&ws[iv.w], pack_key(tv.w, i0 + 3));
    } else if (i0 < E) {
        for (int i = i0; i < E; ++i)
            if (t[i] >= T_HI) atomicMax(&ws[idx[i]], pack_key(t[i], i));
    }
}

// K2: low-t events. The kernel boundary after K1 guarantees K1's atomics are
// visible to plain loads here, so the filter genuinely skips ~92% of nodes'
// events (those whose node max is >= T_HI). Within K2 the table is monotone
// non-decreasing, so a stale read only costs a redundant atomic, never a skip
// error.
__global__ void __launch_bounds__(256)
scatter_lo_kernel(const int* __restrict__ t, const int* __restrict__ idx,
                  unsigned long long* __restrict__ ws, int E) {
    int i0 = (blockIdx.x * blockDim.x + threadIdx.x) * 4;
    if (i0 + 3 < E) {
        int4 tv = *(const int4*)(t + i0);
        int4 iv = *(const int4*)(idx + i0);
        if (tv.x < T_HI) {
            unsigned long long k = pack_key(tv.x, i0 + 0);
            if (ws[iv.x] < k) atomicMax(&ws[iv.x], k);
        }
        if (tv.y < T_HI) {
            unsigned long long k = pack_key(tv.y, i0 + 1);
            if (ws[iv.y] < k) atomicMax(&ws[iv.y], k);
        }
        if (tv.z < T_HI) {
            unsigned long long k = pack_key(tv.z, i0 + 2);
            if (ws[iv.z] < k) atomicMax(&ws[iv.z], k);
        }
        if (tv.w < T_HI) {
            unsigned long long k = pack_key(tv.w, i0 + 3);
            if (ws[iv.w] < k) atomicMax(&ws[iv.w], k);
        }
    } else if (i0 < E) {
        for (int i = i0; i < E; ++i) {
            if (t[i] < T_HI) {
                unsigned long long k = pack_key(t[i], i);
                if (ws[idx[i]] < k) atomicMax(&ws[idx[i]], k);
            }
        }
    }
}

// Gather: 32 lanes per node (D=128 floats = 32 float4), 2 nodes per thread
// for MLP=2. Rows are 512B contiguous -> coalesced within each 32-lane group.
__global__ void __launch_bounds__(256)
gather_kernel(const unsigned long long* __restrict__ ws,
              const float4* __restrict__ msg,
              float4* __restrict__ out, int N, int half) {
    int gid = blockIdx.x * blockDim.x + threadIdx.x;
    int lane = gid & 31;
    int na = gid >> 5;
    if (na >= half) return;
    int nb = na + half;

    unsigned long long ka = ws[na];
    unsigned long long kb = (nb < N) ? ws[nb] : 0ULL;

    float4 va = make_float4(0.f, 0.f, 0.f, 0.f);
    float4 vb = va;
    if (ka != 0ULL) {
        int pa = (int)(unsigned int)(ka & 0xFFFFFFFFULL) - 1;
        va = msg[(size_t)pa * 32 + lane];
    }
    if (kb != 0ULL) {
        int pb = (int)(unsigned int)(kb & 0xFFFFFFFFULL) - 1;
        vb = msg[(size_t)pb * 32 + lane];
    }
    out[(size_t)na * 32 + lane] = va;
    if (nb < N) out[(size_t)nb * 32 + lane] = vb;
}

extern "C" void kernel_launch(void* const* d_in, const int* in_sizes, int n_in,
                              void* d_out, int out_size, void* d_ws, size_t ws_size,
                              hipStream_t stream) {
    const float* msg = (const float*)d_in[0];
    const int* index = (const int*)d_in[1];
    const int* t     = (const int*)d_in[2];
    const int D = 128;
    const int E = in_sizes[0] / D;
    const int N = out_size / D;

    unsigned long long* ws = (unsigned long long*)d_ws;

    {
        int threads = 256;
        int blocks = (N + threads - 1) / threads;
        init_ws_kernel<<<blocks, threads, 0, stream>>>(ws, N);
    }
    {
        int threads = 256;
        int nthreads = (E + 3) / 4;
        int blocks = (nthreads + threads - 1) / threads;
        scatter_hi_kernel<<<blocks, threads, 0, stream>>>(t, index, ws, E);
        scatter_lo_kernel<<<blocks, threads, 0, stream>>>(t, index, ws, E);
    }
    {
        int threads = 256;
        int half = (N + 1) / 2;
        long long total = (long long)half * 32;
        int blocks = (int)((total + threads - 1) / threads);
        gather_kernel<<<blocks, threads, 0, stream>>>(
            ws, (const float4*)msg, (float4*)d_out, N, half);
    }
}